// Round 19
// baseline (198.396 us; speedup 1.0000x reference)
//
#include <hip/hip_runtime.h>
#include <math.h>

#define N_NODES 100000
#define N_EDGES 1600000
#define HD 64
#define NBUCK 128          // dst>>10 -> 98 used buckets
#define BNODES 1024
#define EPB 4096           // edges per block in reorder
#define EPB2 8192          // edges per block in fused hist
#define HB 196             // hist blocks = ceil(E/EPB2)

typedef unsigned short ushort_t;
typedef unsigned char uchar_t;
typedef __attribute__((ext_vector_type(8))) unsigned short ushort8_t;
typedef __attribute__((ext_vector_type(4))) unsigned short ushort4_t;
typedef __attribute__((ext_vector_type(8))) short short8_t;
typedef __attribute__((ext_vector_type(4))) float float4_t;
typedef __attribute__((ext_vector_type(2))) float float2_t;

__device__ __forceinline__ float bf2f(ushort_t h){
  union{unsigned u; float f;} v; v.u = ((unsigned)h)<<16; return v.f;
}
__device__ __forceinline__ ushort_t f2bf(float f){
  union{float f; unsigned u;} v; v.f=f;
  unsigned b = v.u + 0x7FFF + ((v.u>>16)&1);
  return (ushort_t)(b>>16);
}
__device__ __forceinline__ void acc8(float* acc, unsigned ux, unsigned uy, float m){
  float2_t f;
  f=__builtin_amdgcn_cvt_pk_f32_fp8((int)ux,false); acc[0]=fmaf(m,f.x,acc[0]); acc[1]=fmaf(m,f.y,acc[1]);
  f=__builtin_amdgcn_cvt_pk_f32_fp8((int)ux,true ); acc[2]=fmaf(m,f.x,acc[2]); acc[3]=fmaf(m,f.y,acc[3]);
  f=__builtin_amdgcn_cvt_pk_f32_fp8((int)uy,false); acc[4]=fmaf(m,f.x,acc[4]); acc[5]=fmaf(m,f.y,acc[5]);
  f=__builtin_amdgcn_cvt_pk_f32_fp8((int)uy,true ); acc[6]=fmaf(m,f.x,acc[6]); acc[7]=fmaf(m,f.y,acc[7]);
}

// fused: x f32 -> bf16 + fp8 copies; blocks < HB also build a PRIVATE dst
// histogram (bcnt2d[b][bucket]) -- no global atomics, no zeroing needed.
__global__ __launch_bounds__(512) void k_convert_hist(
    const float* __restrict__ in, ushort_t* __restrict__ obf, uchar_t* __restrict__ o8,
    const int* __restrict__ dst, int* __restrict__ bcnt2d, int nfeat, int nedge){
  __shared__ int lh[NBUCK];
  int t=threadIdx.x, b=blockIdx.x;
  bool doHist = (b < HB);
  if(doHist){
    if(t<NBUCK) lh[t]=0;
    __syncthreads();
    int base=b*EPB2;
    #pragma unroll
    for(int j=0;j<16;j++){
      int e=base+t+j*512;
      if(e<nedge) atomicAdd(&lh[dst[e]>>10],1);
    }
  }
  int idx = (b*512+t)*4;
  if(idx+3<nfeat){
    float4 v = *(const float4*)&in[idx];
    ushort2 a; a.x=f2bf(v.x); a.y=f2bf(v.y);
    ushort2 c2; c2.x=f2bf(v.z); c2.y=f2bf(v.w);
    *(ushort2*)&obf[idx] = a;
    *(ushort2*)&obf[idx+2] = c2;
    int p = __builtin_amdgcn_cvt_pk_fp8_f32(v.x, v.y, 0, false);
    p     = __builtin_amdgcn_cvt_pk_fp8_f32(v.z, v.w, p, true);
    *(unsigned int*)&o8[idx] = (unsigned int)p;
  } else {
    for(int k=idx;k<nfeat;k++){
      obf[k]=f2bf(in[k]);
      int p = __builtin_amdgcn_cvt_pk_fp8_f32(in[k], 0.f, 0, false);
      o8[k] = (uchar_t)(p & 0xFF);
    }
  }
  if(doHist){
    __syncthreads();
    if(t<NBUCK) bcnt2d[b*NBUCK+t]=lh[t];
  }
}

// W^T bf16 pre-convert: wt[layer][col][k], k<64 from Wl, k>=64 from Wr.
__global__ void k_prep_w(const float* __restrict__ W1l, const float* __restrict__ W1r,
                         const float* __restrict__ W2l, const float* __restrict__ W2r,
                         const float* __restrict__ W3l, const float* __restrict__ W3r,
                         ushort_t* __restrict__ wt){
  int idx = blockIdx.x*512 + threadIdx.x;   // 0..6143
  int layer = idx>>11;
  int rem = idx & 2047;
  int col = rem >> 5;
  int kg = rem & 31;
  const float* Wl = layer==0? W1l : (layer==1? W2l : W3l);
  const float* Wr = layer==0? W1r : (layer==1? W2r : W3r);
  ushort_t* o = wt + layer*8192 + col*128 + kg*4;
  #pragma unroll
  for(int i=0;i<4;i++){
    int k = kg*4+i;
    float v = (k<64)? Wl[k*64+col] : Wr[(k-64)*64+col];
    o[i]=f2bf(v);
  }
}

// sum private hists -> bucket totals -> exclusive scan
__global__ void k_scan128(const int* __restrict__ bcnt2d, int* __restrict__ gcur, int* __restrict__ gbase){
  __shared__ int s[NBUCK];
  int t=threadIdx.x;
  int v=0;
  int b=0;
  for(; b+4<=HB; b+=4)
    v += bcnt2d[b*NBUCK+t] + bcnt2d[(b+1)*NBUCK+t] + bcnt2d[(b+2)*NBUCK+t] + bcnt2d[(b+3)*NBUCK+t];
  for(; b<HB; ++b) v += bcnt2d[b*NBUCK+t];
  s[t]=v;
  __syncthreads();
  for(int off=1; off<NBUCK; off<<=1){
    int a=(t>=off)? s[t-off]:0;
    __syncthreads();
    s[t]+=a;
    __syncthreads();
  }
  int excl = s[t]-v;
  gcur[t]=excl;
  gbase[t]=excl;
  if(t==NBUCK-1) gbase[NBUCK]=s[t];
}

// packed pair: src (17b) | dstlocal<<17 (10b)
__global__ __launch_bounds__(512) void k_reorder(
    const int* __restrict__ src, const int* __restrict__ dst,
    int* __restrict__ gcur, int* __restrict__ pairs, int n){
  __shared__ int lh[NBUCK];
  __shared__ int lbase[NBUCK];
  int t=threadIdx.x;
  if(t<NBUCK) lh[t]=0;
  __syncthreads();
  int base = blockIdx.x*EPB;
  int bb[8], rr[8], pv[8];
  #pragma unroll
  for(int j=0;j<8;j++){
    int e = base + t + j*512;
    if(e<n){
      int d=dst[e];
      int b=d>>10;
      rr[j]=atomicAdd(&lh[b],1);
      bb[j]=b;
      pv[j]=src[e] | ((d & 1023)<<17);
    } else bb[j]=-1;
  }
  __syncthreads();
  if(t<NBUCK && lh[t]) lbase[t]=atomicAdd(&gcur[t], lh[t]);
  __syncthreads();
  #pragma unroll
  for(int j=0;j<8;j++){
    if(bb[j]>=0){
      int pos = lbase[bb[j]] + rr[j];
      pairs[pos] = pv[j];
    }
  }
}

// One block per bucket: LDS hist over 1024 local nodes -> scan -> rowptr/invdeg
// -> LDS-cursor scatter into the bucket's private csr window (one XCD's L2).
__global__ __launch_bounds__(512) void k_bucket_csr(
    const int* __restrict__ pairs, const int* __restrict__ gbase,
    int* __restrict__ rowptr, float* __restrict__ invdeg,
    int* __restrict__ csr, int nnodes, int nedges){
  __shared__ int cnt[BNODES];
  __shared__ int part[512];
  int t=threadIdx.x, b=blockIdx.x;
  int nb0 = b*BNODES;
  int e0 = gbase[b], e1 = gbase[b+1];
  cnt[t]=0; cnt[t+512]=0;
  __syncthreads();
  for(int e=e0+t; e<e1; e+=512) atomicAdd(&cnt[pairs[e]>>17], 1);
  __syncthreads();
  int c0 = cnt[2*t], c1 = cnt[2*t+1];
  part[t] = c0+c1;
  __syncthreads();
  for(int off=1; off<512; off<<=1){
    int a=(t>=off)? part[t-off]:0;
    __syncthreads();
    part[t]+=a;
    __syncthreads();
  }
  int base = part[t]-(c0+c1);
  int ex0 = base, ex1 = base+c0;
  int n_0 = nb0+2*t, n_1 = nb0+2*t+1;
  if(n_0<nnodes){ rowptr[n_0]=e0+ex0; invdeg[n_0]=1.0f/fmaxf((float)c0,1.0f); }
  if(n_1<nnodes){ rowptr[n_1]=e0+ex1; invdeg[n_1]=1.0f/fmaxf((float)c1,1.0f); }
  if(b==0 && t==0) rowptr[nnodes]=nedges;
  cnt[2*t]=ex0; cnt[2*t+1]=ex1;      // become cursors
  __syncthreads();
  for(int e=e0+t; e<e1; e+=512){
    int p = pairs[e];
    int pos = atomicAdd(&cnt[p>>17], 1);
    csr[e0+pos] = p & 0x1FFFF;
  }
}

// FUSED layer: gather (8 waves x 2 nodes, fp8, jammed tails) -> LDS agg ->
// MFMA dense (4 waves, M=16 tile) -> epilogue (bias+relu, bf16+fp8 stores,
// JK dot, sigmoid on last layer). 16 nodes/block, grid 6250.
__global__ __launch_bounds__(512) void k_fused(
    const ushort_t* __restrict__ hin, const uchar_t* __restrict__ hin8,
    const ushort_t* __restrict__ wt,
    const float* __restrict__ bvec, const float* __restrict__ wseg, const float* __restrict__ blin,
    const int* __restrict__ rowptr, const int* __restrict__ csr, const float* __restrict__ invdeg,
    ushort_t* __restrict__ hout, uchar_t* __restrict__ h8out,
    float* __restrict__ pacc, float* __restrict__ finout, int first, int nnodes)
{
  __shared__ __align__(16) ushort_t sWt[64][136];
  __shared__ __align__(16) ushort_t sAgg[16][72];
  __shared__ __align__(16) ushort_t sOut[16][72];
  __shared__ float sB[64], sS[64];
  int t=threadIdx.x;
  int n0=blockIdx.x*16;

  // stage W^T bf16 (16KB contiguous from wt)
  {
    int col=t>>3, sub=t&7;
    const ushort8_t* src=(const ushort8_t*)(wt + col*128);
    ushort8_t* dst=(ushort8_t*)&sWt[col][0];
    dst[sub*2]   = src[sub*2];
    dst[sub*2+1] = src[sub*2+1];
  }
  if(t<64){ sB[t]=bvec[t]; sS[t]=wseg[t]; }

  // ---- gather phase: wave wid -> nodes n0+2*wid, n0+2*wid+1
  {
    int lane=t&63, wid=t>>6;
    int nA=n0+wid*2, nB=nA+1;
    if(nA<nnodes){
      bool hasB=(nB<nnodes);
      int slot=lane>>3, c=lane&7;
      int rA0=rowptr[nA], rA1=rowptr[nA+1];
      int rB0=rA1, rB1=hasB? rowptr[nB+1] : rA1;
      float idgA=invdeg[nA];
      float idgB=hasB? invdeg[nB] : 0.f;
      float aA[8]={0,0,0,0,0,0,0,0}, aB[8]={0,0,0,0,0,0,0,0};
      int ca=(rA1>rA0)? rA1-1 : 0;
      int cb=(rB1>rB0)? rB1-1 : 0;
      {  // prologue: batch0 of A and B in flight together (4 gather VMEMs)
        int i1=rA0+slot, i2=rA0+8+slot;
        int j1=rB0+slot, j2=rB0+8+slot;
        int sA1=csr[min(i1,ca)], sA2=csr[min(i2,ca)];
        int sB1=csr[min(j1,cb)], sB2=csr[min(j2,cb)];
        uint2 uA1=*(const uint2*)&hin8[(size_t)sA1*HD + c*8];
        uint2 uA2=*(const uint2*)&hin8[(size_t)sA2*HD + c*8];
        uint2 uB1=*(const uint2*)&hin8[(size_t)sB1*HD + c*8];
        uint2 uB2=*(const uint2*)&hin8[(size_t)sB2*HD + c*8];
        acc8(aA,uA1.x,uA1.y,(i1<rA1)?1.f:0.f);
        acc8(aA,uA2.x,uA2.y,(i2<rA1)?1.f:0.f);
        acc8(aB,uB1.x,uB1.y,(j1<rB1)?1.f:0.f);
        acc8(aB,uB2.x,uB2.y,(j2<rB1)?1.f:0.f);
      }
      int eA=rA0+16, eB=rB0+16;
      for(; eA<rA1 && eB<rB1; eA+=16, eB+=16){   // jammed tails: 2 chains
        int i1=eA+slot, i2=eA+8+slot;
        int j1=eB+slot, j2=eB+8+slot;
        int sA1=csr[min(i1,ca)], sA2=csr[min(i2,ca)];
        int sB1=csr[min(j1,cb)], sB2=csr[min(j2,cb)];
        uint2 uA1=*(const uint2*)&hin8[(size_t)sA1*HD + c*8];
        uint2 uA2=*(const uint2*)&hin8[(size_t)sA2*HD + c*8];
        uint2 uB1=*(const uint2*)&hin8[(size_t)sB1*HD + c*8];
        uint2 uB2=*(const uint2*)&hin8[(size_t)sB2*HD + c*8];
        acc8(aA,uA1.x,uA1.y,(i1<rA1)?1.f:0.f);
        acc8(aA,uA2.x,uA2.y,(i2<rA1)?1.f:0.f);
        acc8(aB,uB1.x,uB1.y,(j1<rB1)?1.f:0.f);
        acc8(aB,uB2.x,uB2.y,(j2<rB1)?1.f:0.f);
      }
      for(; eA<rA1; eA+=16){
        int i1=eA+slot, i2=eA+8+slot;
        int s1=csr[min(i1,ca)], s2=csr[min(i2,ca)];
        uint2 u1=*(const uint2*)&hin8[(size_t)s1*HD + c*8];
        uint2 u2=*(const uint2*)&hin8[(size_t)s2*HD + c*8];
        acc8(aA,u1.x,u1.y,(i1<rA1)?1.f:0.f);
        acc8(aA,u2.x,u2.y,(i2<rA1)?1.f:0.f);
      }
      for(; eB<rB1; eB+=16){
        int i1=eB+slot, i2=eB+8+slot;
        int s1=csr[min(i1,cb)], s2=csr[min(i2,cb)];
        uint2 u1=*(const uint2*)&hin8[(size_t)s1*HD + c*8];
        uint2 u2=*(const uint2*)&hin8[(size_t)s2*HD + c*8];
        acc8(aB,u1.x,u1.y,(i1<rB1)?1.f:0.f);
        acc8(aB,u2.x,u2.y,(i2<rB1)?1.f:0.f);
      }
      #pragma unroll
      for(int off=8; off<64; off<<=1){
        #pragma unroll
        for(int j=0;j<8;j++){
          aA[j] += __shfl_xor(aA[j], off, 64);
          aB[j] += __shfl_xor(aB[j], off, 64);
        }
      }
      if(slot==0){
        ushort8_t o;
        #pragma unroll
        for(int j=0;j<8;j++) o[j] = f2bf(aA[j]*idgA);
        *(ushort8_t*)&sAgg[wid*2][c*8] = o;
        if(hasB){
          #pragma unroll
          for(int j=0;j<8;j++) o[j] = f2bf(aB[j]*idgB);
          *(ushort8_t*)&sAgg[wid*2+1][c*8] = o;
        }
      }
    }
  }
  __syncthreads();

  // ---- dense phase (waves 0..3): wave wv computes cols wv*16..wv*16+15
  {
    int wv = t>>6;
    if(wv<4){
      int lane=t&63, r16=lane&15, g4=lane>>4;
      float4_t acc = {0.f,0.f,0.f,0.f};
      #pragma unroll
      for(int ks=0; ks<4; ++ks){
        short8_t aF;
        if(ks<2){
          aF = *(const short8_t*)&sAgg[r16][ks*32 + g4*8];
        } else {
          int node = n0 + r16;
          if(node >= nnodes) node = nnodes-1;
          aF = *(const short8_t*)&hin[(size_t)node*HD + (ks&1)*32 + g4*8];
        }
        short8_t bF = *(const short8_t*)&sWt[wv*16 + r16][ks*32 + g4*8];
        acc = __builtin_amdgcn_mfma_f32_16x16x32_bf16(aF, bF, acc, 0,0,0);
      }
      int col = wv*16 + r16;
      #pragma unroll
      for(int r=0;r<4;r++){
        int nl = g4*4 + r;
        float v = fmaxf(acc[r] + sB[col], 0.f);
        sOut[nl][col] = f2bf(v);
      }
    }
  }
  __syncthreads();

  // ---- epilogue (threads 0..255): stores + JK dot (+sigmoid)
  if(t<256){
    int nl=t>>4, j=t&15, c0=j*4;
    int node=n0+nl;
    ushort4_t v = *(const ushort4_t*)&sOut[nl][c0];
    float f0=bf2f(v[0]), f1=bf2f(v[1]), f2v=bf2f(v[2]), f3=bf2f(v[3]);
    float p = f0*sS[c0] + f1*sS[c0+1] + f2v*sS[c0+2] + f3*sS[c0+3];
    if(!finout && node<nnodes){
      *(ushort4_t*)&hout[(size_t)node*HD + c0] = v;
      int q = __builtin_amdgcn_cvt_pk_fp8_f32(f0, f1, 0, false);
      q     = __builtin_amdgcn_cvt_pk_fp8_f32(f2v, f3, q, true);
      *(unsigned*)&h8out[(size_t)node*HD + c0] = (unsigned)q;
    }
    #pragma unroll
    for(int off=1; off<16; off<<=1) p += __shfl_xor(p, off, 16);
    if(j==0 && node<nnodes){
      float q = first ? (blin[0]+p) : (pacc[node]+p);
      if(finout) finout[node] = 1.0f/(1.0f+expf(-q));
      else pacc[node] = q;
    }
  }
}

extern "C" void kernel_launch(void* const* d_in, const int* in_sizes, int n_in,
                              void* d_out, int out_size, void* d_ws, size_t ws_size,
                              hipStream_t stream){
  const float* x    =(const float*)d_in[0];
  const int*   ei   =(const int*)  d_in[1];
  const float* W1l  =(const float*)d_in[2];
  const float* b1   =(const float*)d_in[3];
  const float* W1r  =(const float*)d_in[4];
  const float* W2l  =(const float*)d_in[5];
  const float* b2   =(const float*)d_in[6];
  const float* W2r  =(const float*)d_in[7];
  const float* W3l  =(const float*)d_in[8];
  const float* b3   =(const float*)d_in[9];
  const float* W3r  =(const float*)d_in[10];
  const float* Wlin =(const float*)d_in[11];
  const float* blin =(const float*)d_in[12];
  float* out=(float*)d_out;

  const int N=N_NODES, E=N_EDGES;
  char* ws=(char*)d_ws;
  size_t off=0;
  auto take=[&](size_t bytes)->char*{ char* p=ws+off; off=(off+bytes+255)&~(size_t)255; return p; };
  int*      bcnt2d   =(int*)     take((size_t)HB*NBUCK*4);
  int*      gcur     =(int*)     take((size_t)NBUCK*4);
  int*      gbase    =(int*)     take((size_t)(NBUCK+1)*4);
  int*      rowptr   =(int*)     take((size_t)(N+1)*4);
  int*      csr      =(int*)     take((size_t)E*4);
  int*      pairs    =(int*)     take((size_t)E*4);
  float*    invdeg   =(float*)   take((size_t)N*4);
  ushort_t* wt3      =(ushort_t*)take((size_t)3*8192*2);
  ushort_t* xbf      =(ushort_t*)take((size_t)N*HD*2);
  ushort_t* hbfA     =(ushort_t*)take((size_t)N*HD*2);
  ushort_t* hbfB     =(ushort_t*)take((size_t)N*HD*2);
  uchar_t*  x8       =(uchar_t*) take((size_t)N*HD);
  uchar_t*  h8A      =(uchar_t*) take((size_t)N*HD);
  uchar_t*  h8B      =(uchar_t*) take((size_t)N*HD);
  float*    pacc     =(float*)   take((size_t)N*4);

  const int RB=(E+EPB-1)/EPB;           // 391 (reorder)
  const int CB=(N*HD/4+511)/512;        // 3125 fused convert+hist blocks
  const int BB=(N+BNODES-1)/BNODES;     // 98 buckets

  k_convert_hist<<<CB, 512, 0, stream>>>(x, xbf, x8, ei+E, bcnt2d, N*HD, E);
  k_prep_w      <<<12, 512, 0, stream>>>(W1l,W1r,W2l,W2r,W3l,W3r, wt3);
  k_scan128     <<<1, NBUCK, 0, stream>>>(bcnt2d, gcur, gbase);
  k_reorder     <<<RB, 512, 0, stream>>>(ei, ei+E, gcur, pairs, E);
  k_bucket_csr  <<<BB, 512, 0, stream>>>(pairs, gbase, rowptr, invdeg, csr, N, E);

  dim3 gf((N+15)/16);                   // 6250 blocks, 16 nodes/block

  k_fused<<<gf, 512, 0, stream>>>(xbf,  x8,  wt3,        b1, Wlin+0,   blin, rowptr, csr, invdeg, hbfA, h8A, pacc, (float*)nullptr, 1, N);
  k_fused<<<gf, 512, 0, stream>>>(hbfA, h8A, wt3+8192,   b2, Wlin+64,  blin, rowptr, csr, invdeg, hbfB, h8B, pacc, (float*)nullptr, 0, N);
  k_fused<<<gf, 512, 0, stream>>>(hbfB, h8B, wt3+16384,  b3, Wlin+128, blin, rowptr, csr, invdeg, hbfA, h8A, pacc, out, 0, N);
}